// Round 1
// baseline (869.844 us; speedup 1.0000x reference)
//
#include <hip/hip_runtime.h>
#include <hip/hip_bf16.h>

// Problem constants (B,H,S,D) = (4,16,2048,128), causal mask.
constexpr int S_LEN = 2048;
constexpr int D_DIM = 128;

typedef __attribute__((ext_vector_type(8))) short short8;  // 8 x bf16 (4 VGPRs)
typedef __attribute__((ext_vector_type(4))) float f32x4;   // MFMA accumulator

// fp32 -> bf16 round-to-nearest-even (inputs are finite; no NaN handling needed)
__device__ inline short f2bf(float f) {
    unsigned u = __builtin_bit_cast(unsigned, f);
    u += 0x7fffu + ((u >> 16) & 1u);
    return (short)(u >> 16);
}

// LDS strides (elements). 136*2=272B and 72*2=144B are 16B-aligned for ds_*_b128,
// and give 2-way bank aliasing on fragment reads (free per m136).
constexpr int SK_STRIDE = 136;   // K tile: 64 keys x 128 d
constexpr int SVT_STRIDE = 72;   // V^T tile: 128 d x 64 keys
constexpr int SP_STRIDE = 72;    // P tile: 64 q x 64 keys

__global__ __launch_bounds__(256, 2)
void fa_causal_kernel(const float* __restrict__ Q, const float* __restrict__ K,
                      const float* __restrict__ V, float* __restrict__ Out) {
    __shared__ short sK[64 * SK_STRIDE];
    __shared__ short sVt[128 * SVT_STRIDE];
    __shared__ short sP[64 * SP_STRIDE];

    const int tid  = threadIdx.x;
    const int wid  = tid >> 6;       // wave id 0..3 -> owns q rows [16*wid, 16*wid+16)
    const int lane = tid & 63;
    const int quad = lane >> 4;      // 0..3
    const int l16  = lane & 15;

    // Reverse q-tile order: heaviest (most k-tiles) blocks launch first.
    const int qt = (int)(gridDim.x - 1 - blockIdx.x);
    const int bh = blockIdx.y;
    const size_t base = (size_t)bh * S_LEN * D_DIM;
    const int q0 = qt * 64;

    const float scale = 0.08838834764831845f;  // 1/sqrt(128)

    // ---- Load Q fragments once (A-operand layout: m=lane&15, k=quad*8+j) ----
    short8 q_frag[4];
    {
        const int qrow = q0 + wid * 16 + l16;
        const float* qp = Q + base + (size_t)qrow * D_DIM;
        for (int kk = 0; kk < 4; ++kk) {
            const int d0 = kk * 32 + quad * 8;
            float4 a = *reinterpret_cast<const float4*>(qp + d0);
            float4 b = *reinterpret_cast<const float4*>(qp + d0 + 4);
            short8 f;
            f[0] = f2bf(a.x * scale); f[1] = f2bf(a.y * scale);
            f[2] = f2bf(a.z * scale); f[3] = f2bf(a.w * scale);
            f[4] = f2bf(b.x * scale); f[5] = f2bf(b.y * scale);
            f[6] = f2bf(b.z * scale); f[7] = f2bf(b.w * scale);
            q_frag[kk] = f;
        }
    }

    // O accumulator: 8 n-tiles (D=128) x 4 rows (C/D layout: row=quad*4+reg).
    f32x4 o_acc[8];
    for (int i = 0; i < 8; ++i) o_acc[i] = f32x4{0.f, 0.f, 0.f, 0.f};
    // Per-lane online-softmax state for the 4 rows (quad*4+r) this lane holds.
    float m_i[4], l_i[4];
    for (int r = 0; r < 4; ++r) { m_i[r] = -1e30f; l_i[r] = 0.f; }

    const int nkt = qt + 1;  // causal: k-tiles 0..qt
    for (int kt = 0; kt < nkt; ++kt) {
        // ---- Stage K tile to LDS (row-major, bf16) ----
        for (int it = 0; it < 4; ++it) {
            const int idx = (it * 256 + tid) * 8;   // 8192 elems total
            const int key = idx >> 7;
            const int d   = idx & 127;
            const float* kp = K + base + (size_t)(kt * 64 + key) * D_DIM + d;
            float4 a = *reinterpret_cast<const float4*>(kp);
            float4 b = *reinterpret_cast<const float4*>(kp + 4);
            short8 f;
            f[0]=f2bf(a.x); f[1]=f2bf(a.y); f[2]=f2bf(a.z); f[3]=f2bf(a.w);
            f[4]=f2bf(b.x); f[5]=f2bf(b.y); f[6]=f2bf(b.z); f[7]=f2bf(b.w);
            *reinterpret_cast<short8*>(&sK[key * SK_STRIDE + d]) = f;
        }
        // ---- Stage V tile transposed (sVt[d][key], bf16) ----
        for (int it = 0; it < 4; ++it) {
            const int idx = (it * 256 + tid) * 8;
            const int key = idx >> 7;
            const int d   = idx & 127;
            const float* vp = V + base + (size_t)(kt * 64 + key) * D_DIM + d;
            float4 a = *reinterpret_cast<const float4*>(vp);
            float4 b = *reinterpret_cast<const float4*>(vp + 4);
            float vals[8] = {a.x, a.y, a.z, a.w, b.x, b.y, b.z, b.w};
            for (int j = 0; j < 8; ++j)
                sVt[(d + j) * SVT_STRIDE + key] = f2bf(vals[j]);
        }
        __syncthreads();

        // ---- S = Q * K^T for this wave's 16 rows x 64 keys ----
        f32x4 s_acc[4];
        for (int ct = 0; ct < 4; ++ct) {
            f32x4 acc = f32x4{0.f, 0.f, 0.f, 0.f};
            for (int kk = 0; kk < 4; ++kk) {
                short8 kf = *reinterpret_cast<const short8*>(
                    &sK[(ct * 16 + l16) * SK_STRIDE + kk * 32 + quad * 8]);
                acc = __builtin_amdgcn_mfma_f32_16x16x32_bf16(q_frag[kk], kf, acc, 0, 0, 0);
            }
            s_acc[ct] = acc;
        }

        // ---- Causal mask (diagonal tile only; earlier tiles fully valid) ----
        if (kt == qt) {
            for (int ct = 0; ct < 4; ++ct) {
                const int kg = kt * 64 + ct * 16 + l16;   // C-layout col
                for (int r = 0; r < 4; ++r) {
                    const int qg = q0 + wid * 16 + quad * 4 + r;  // C-layout row
                    if (kg > qg) s_acc[ct][r] = -1e30f;
                }
            }
        }

        // ---- Online softmax (register-only; rows live in 16-lane groups) ----
        float tm[4];
        for (int r = 0; r < 4; ++r)
            tm[r] = fmaxf(fmaxf(s_acc[0][r], s_acc[1][r]),
                          fmaxf(s_acc[2][r], s_acc[3][r]));
        for (int off = 1; off < 16; off <<= 1)
            for (int r = 0; r < 4; ++r)
                tm[r] = fmaxf(tm[r], __shfl_xor(tm[r], off));

        float alpha[4], m_new[4], rs[4];
        for (int r = 0; r < 4; ++r) {
            m_new[r] = fmaxf(m_i[r], tm[r]);
            alpha[r] = __expf(m_i[r] - m_new[r]);
            rs[r] = 0.f;
        }
        for (int ct = 0; ct < 4; ++ct)
            for (int r = 0; r < 4; ++r) {
                float p = __expf(s_acc[ct][r] - m_new[r]);
                s_acc[ct][r] = p;
                rs[r] += p;
            }
        for (int off = 1; off < 16; off <<= 1)
            for (int r = 0; r < 4; ++r)
                rs[r] += __shfl_xor(rs[r], off);
        for (int r = 0; r < 4; ++r) {
            l_i[r] = alpha[r] * l_i[r] + rs[r];
            m_i[r] = m_new[r];
        }
        for (int nt = 0; nt < 8; ++nt)
            for (int r = 0; r < 4; ++r)
                o_acc[nt][r] *= alpha[r];

        // ---- P (bf16) -> LDS: C-layout write, A-layout read (m120 pattern) ----
        for (int ct = 0; ct < 4; ++ct)
            for (int r = 0; r < 4; ++r)
                sP[(wid * 16 + quad * 4 + r) * SP_STRIDE + ct * 16 + l16] =
                    f2bf(s_acc[ct][r]);
        // Same-wave write->read: in-order LDS pipe + compiler lgkmcnt handles it.

        // ---- O += P * V ----
        for (int nt = 0; nt < 8; ++nt) {
            for (int k2 = 0; k2 < 2; ++k2) {
                short8 pf = *reinterpret_cast<const short8*>(
                    &sP[(wid * 16 + l16) * SP_STRIDE + k2 * 32 + quad * 8]);
                short8 vf = *reinterpret_cast<const short8*>(
                    &sVt[(nt * 16 + l16) * SVT_STRIDE + k2 * 32 + quad * 8]);
                o_acc[nt] = __builtin_amdgcn_mfma_f32_16x16x32_bf16(pf, vf, o_acc[nt], 0, 0, 0);
            }
        }
        __syncthreads();  // protect sK/sVt/sP before next tile's staging
    }

    // ---- Epilogue: normalize by l_i, store fp32 ----
    for (int nt = 0; nt < 8; ++nt) {
        for (int r = 0; r < 4; ++r) {
            const int qrow = q0 + wid * 16 + quad * 4 + r;
            Out[base + (size_t)qrow * D_DIM + nt * 16 + l16] = o_acc[nt][r] / l_i[r];
        }
    }
}

extern "C" void kernel_launch(void* const* d_in, const int* in_sizes, int n_in,
                              void* d_out, int out_size, void* d_ws, size_t ws_size,
                              hipStream_t stream) {
    const float* Q = (const float*)d_in[0];
    const float* K = (const float*)d_in[1];
    const float* V = (const float*)d_in[2];
    // d_in[3] is the causal mask; mask is structural (tril), applied analytically.
    float* Out = (float*)d_out;

    dim3 grid(S_LEN / 64, 4 * 16);  // (q-tiles, B*H)
    fa_causal_kernel<<<grid, 256, 0, stream>>>(Q, K, V, Out);
}

// Round 2
// 469.643 us; speedup vs baseline: 1.8521x; 1.8521x over previous
//
#include <hip/hip_runtime.h>
#include <hip/hip_bf16.h>

// (B,H,S,D) = (4,16,2048,128), causal.
constexpr int S_LEN = 2048;
constexpr int D_DIM = 128;

typedef __attribute__((ext_vector_type(8))) short short8;  // 8 x bf16
typedef __attribute__((ext_vector_type(4))) float f32x4;   // MFMA acc

__device__ inline short f2bf(float f) {
    unsigned u = __builtin_bit_cast(unsigned, f);
    u += 0x7fffu + ((u >> 16) & 1u);
    return (short)(u >> 16);
}

// LDS strides in shorts. All fragment reads are 16B-aligned b128 because the
// XOR swizzle permutes whole 8-short chunks only.
constexpr int SK_STRIDE  = 136;  // K tile 64x128 row-major (~2-way on r/w: free)
constexpr int SVT_STRIDE = 72;   // V^T tile 128x64, chunk-swizzled
constexpr int SP_STRIDE  = 72;   // P tile 64x64, chunk-swizzled, overlaid on sK

__global__ __launch_bounds__(256, 4)
void fa_causal_kernel(const float* __restrict__ Q, const float* __restrict__ K,
                      const float* __restrict__ V, float* __restrict__ Out) {
    __shared__ short sK[64 * SK_STRIDE];      // 17,408 B; reused as sP after QK
    __shared__ short sVt[128 * SVT_STRIDE];   // 18,432 B  (total 35,840 B -> 4 blk/CU)
    short* sP = sK;

    const int tid  = threadIdx.x;
    const int wid  = tid >> 6;
    const int lane = tid & 63;
    const int quad = lane >> 4;
    const int l16  = lane & 15;

    const int x  = blockIdx.x;   // 0..15: pair (31-x, x) -> uniform 33 k-tiles/block
    const int bh = blockIdx.y;
    const size_t base = (size_t)bh * S_LEN * D_DIM;
    const float scale = 0.08838834764831845f;  // 1/sqrt(128)

    for (int pi = 0; pi < 2; ++pi) {
        const int qt = (pi == 0) ? (31 - x) : x;
        const int q0 = qt * 64;

        // ---- Q fragments (A-layout: m=lane&15, k=quad*8+j), pre-scaled ----
        short8 q_frag[4];
        {
            const float* qp = Q + base + (size_t)(q0 + wid * 16 + l16) * D_DIM;
            for (int kk = 0; kk < 4; ++kk) {
                const int d0 = kk * 32 + quad * 8;
                float4 a = *reinterpret_cast<const float4*>(qp + d0);
                float4 b = *reinterpret_cast<const float4*>(qp + d0 + 4);
                short8 f;
                f[0]=f2bf(a.x*scale); f[1]=f2bf(a.y*scale);
                f[2]=f2bf(a.z*scale); f[3]=f2bf(a.w*scale);
                f[4]=f2bf(b.x*scale); f[5]=f2bf(b.y*scale);
                f[6]=f2bf(b.z*scale); f[7]=f2bf(b.w*scale);
                q_frag[kk] = f;
            }
        }

        f32x4 o_acc[8];
        for (int i = 0; i < 8; ++i) o_acc[i] = f32x4{0.f,0.f,0.f,0.f};
        float m_i[4], l_i[4];
        for (int r = 0; r < 4; ++r) { m_i[r] = -1e30f; l_i[r] = 0.f; }

        for (int kt = 0; kt <= qt; ++kt) {
            // ---- Stage K tile (row-major bf16, b128 writes) ----
            for (int it = 0; it < 4; ++it) {
                const int idx = (it * 256 + tid) * 8;
                const int key = idx >> 7, d = idx & 127;
                const float* kp = K + base + (size_t)(kt * 64 + key) * D_DIM + d;
                float4 a = *reinterpret_cast<const float4*>(kp);
                float4 b = *reinterpret_cast<const float4*>(kp + 4);
                short8 f;
                f[0]=f2bf(a.x); f[1]=f2bf(a.y); f[2]=f2bf(a.z); f[3]=f2bf(a.w);
                f[4]=f2bf(b.x); f[5]=f2bf(b.y); f[6]=f2bf(b.z); f[7]=f2bf(b.w);
                *reinterpret_cast<short8*>(&sK[key * SK_STRIDE + d]) = f;
            }
            // ---- Stage V transposed, chunk-swizzled: elem (row=d,key) at
            //      row*72 + ((key>>3)^((row>>3)&7))*8 + (key&7)  ----
            for (int it = 0; it < 4; ++it) {
                const int idx = (it * 256 + tid) * 8;
                const int key = idx >> 7, d = idx & 127;
                const int kc = key >> 3, kw = key & 7;
                const float* vp = V + base + (size_t)(kt * 64 + key) * D_DIM + d;
                float4 a = *reinterpret_cast<const float4*>(vp);
                float4 b = *reinterpret_cast<const float4*>(vp + 4);
                float vals[8] = {a.x,a.y,a.z,a.w,b.x,b.y,b.z,b.w};
                const int rc = (d >> 3) & 7;      // constant over j (d multiple of 8)
                const int cs = (kc ^ rc) * 8 + kw;
                for (int j = 0; j < 8; ++j)
                    sVt[(d + j) * SVT_STRIDE + cs] = f2bf(vals[j]);
            }
            __syncthreads();

            // ---- S = Q K^T (this wave's 16 rows x 64 keys) ----
            f32x4 s_acc[4];
            for (int ct = 0; ct < 4; ++ct) {
                f32x4 acc = f32x4{0.f,0.f,0.f,0.f};
                for (int kk = 0; kk < 4; ++kk) {
                    short8 kf = *reinterpret_cast<const short8*>(
                        &sK[(ct * 16 + l16) * SK_STRIDE + kk * 32 + quad * 8]);
                    acc = __builtin_amdgcn_mfma_f32_16x16x32_bf16(q_frag[kk], kf, acc, 0, 0, 0);
                }
                s_acc[ct] = acc;
            }

            // ---- Causal mask on the diagonal tile ----
            if (kt == qt) {
                for (int ct = 0; ct < 4; ++ct) {
                    const int kg = ct * 16 + l16;
                    for (int r = 0; r < 4; ++r)
                        if (kg > wid * 16 + quad * 4 + r) s_acc[ct][r] = -1e30f;
                }
            }

            // ---- Online softmax (registers + 16-lane shuffles) ----
            float tm[4];
            for (int r = 0; r < 4; ++r)
                tm[r] = fmaxf(fmaxf(s_acc[0][r], s_acc[1][r]),
                              fmaxf(s_acc[2][r], s_acc[3][r]));
            for (int off = 1; off < 16; off <<= 1)
                for (int r = 0; r < 4; ++r)
                    tm[r] = fmaxf(tm[r], __shfl_xor(tm[r], off));
            float alpha[4], m_new[4], rs[4];
            for (int r = 0; r < 4; ++r) {
                m_new[r] = fmaxf(m_i[r], tm[r]);
                alpha[r] = __expf(m_i[r] - m_new[r]);
                rs[r] = 0.f;
            }
            for (int ct = 0; ct < 4; ++ct)
                for (int r = 0; r < 4; ++r) {
                    float p = __expf(s_acc[ct][r] - m_new[r]);
                    s_acc[ct][r] = p;
                    rs[r] += p;
                }
            for (int off = 1; off < 16; off <<= 1)
                for (int r = 0; r < 4; ++r)
                    rs[r] += __shfl_xor(rs[r], off);
            for (int r = 0; r < 4; ++r) {
                l_i[r] = alpha[r] * l_i[r] + rs[r];
                m_i[r] = m_new[r];
            }
            for (int nt = 0; nt < 8; ++nt)
                for (int r = 0; r < 4; ++r)
                    o_acc[nt][r] *= alpha[r];

            // sK reads (all waves) must finish before P overwrites the region.
            __syncthreads();

            // ---- P -> LDS (bf16, chunk-swizzled): (row,col) at
            //      row*72 + ((col>>3)^((row>>2)&7))*8 + (col&7) ----
            for (int ct = 0; ct < 4; ++ct)
                for (int r = 0; r < 4; ++r) {
                    const int row = wid * 16 + quad * 4 + r;
                    const int col = ct * 16 + l16;
                    sP[row * SP_STRIDE + (((col >> 3) ^ ((row >> 2) & 7)) << 3) + (col & 7)]
                        = f2bf(s_acc[ct][r]);
                }
            // Same-wave write->read: in-order LDS pipe handles the dependency.

            // ---- O += P V ----
            {
                const int prow = wid * 16 + l16;
                const int pxr  = (prow >> 2) & 7;
                for (int nt = 0; nt < 8; ++nt) {
                    const int vrow = nt * 16 + l16;
                    const int vxr  = (vrow >> 3) & 7;
                    for (int k2 = 0; k2 < 2; ++k2) {
                        const int chunk = k2 * 4 + quad;
                        short8 pf = *reinterpret_cast<const short8*>(
                            &sP[prow * SP_STRIDE + ((chunk ^ pxr) << 3)]);
                        short8 vf = *reinterpret_cast<const short8*>(
                            &sVt[vrow * SVT_STRIDE + ((chunk ^ vxr) << 3)]);
                        o_acc[nt] = __builtin_amdgcn_mfma_f32_16x16x32_bf16(pf, vf, o_acc[nt], 0, 0, 0);
                    }
                }
            }
            __syncthreads();  // protect sK/sP/sVt before next tile's staging
        }

        // ---- Epilogue ----
        for (int nt = 0; nt < 8; ++nt)
            for (int r = 0; r < 4; ++r) {
                const int qrow = q0 + wid * 16 + quad * 4 + r;
                Out[base + (size_t)qrow * D_DIM + nt * 16 + l16] = o_acc[nt][r] / l_i[r];
            }
    }
}

extern "C" void kernel_launch(void* const* d_in, const int* in_sizes, int n_in,
                              void* d_out, int out_size, void* d_ws, size_t ws_size,
                              hipStream_t stream) {
    const float* Q = (const float*)d_in[0];
    const float* K = (const float*)d_in[1];
    const float* V = (const float*)d_in[2];
    float* Out = (float*)d_out;
    dim3 grid(16, 4 * 16);  // paired q-tiles x (B*H); 1024 uniform blocks = 4/CU
    fa_causal_kernel<<<grid, 256, 0, stream>>>(Q, K, V, Out);
}